// Round 3
// baseline (77.678 us; speedup 1.0000x reference)
//
#include <hip/hip_runtime.h>

typedef unsigned int u32;
typedef unsigned short u16;
typedef __attribute__((ext_vector_type(8))) __bf16 bf16x8;
typedef __attribute__((ext_vector_type(4))) float f32x4;
typedef __attribute__((ext_vector_type(4))) u32 u32x4;

#define K_DIM 4096
#define N_DIM 14336
#define BM 128
#define BN 64
#define BK 64
#define NT (K_DIM / BK)   // 64 K-steps
#define NBLK 448          // (256/128) * (14336/64)
#define LDA 72            // padded row stride in u16 (144 B)
#define LDB 72

// truncating pack of two f32 into (bf16(hi)<<16 | bf16(lo)) — one v_perm_b32
__device__ __forceinline__ u32 pack_trunc(float lo, float hi) {
  return __builtin_amdgcn_perm(__float_as_uint(hi), __float_as_uint(lo), 0x07060302u);
}

__global__ __launch_bounds__(256, 2) void kivi_gemm(
    const float* __restrict__ X,    // x upconverted to f32 [256][4096]
    const int* __restrict__ QW,     // [512][14336] packed int4 (nibble j -> k = row*8 + j)
    const float* __restrict__ S,    // [32][14336]
    const float* __restrict__ Z,    // [32][14336]
    float* __restrict__ O)          // out f32 [256][14336]
{
  __shared__ __align__(16) u16 As[2][BM][LDA];  // 36,864 B
  __shared__ __align__(16) u16 Bs[2][BN][LDB];  // 18,432 B

  const int tid  = threadIdx.x;
  const int lane = tid & 63;
  const int w    = tid >> 6;

  // XCD-aware bijective swizzle: 448 = 8*56
  const int b  = blockIdx.x;
  const int L  = (b & 7) * 56 + (b >> 3);
  const int m0 = (L & 1) * BM;
  const int n0 = (L >> 1) * BN;

  // B staging ownership
  const int ncol  = tid & 63;
  const int k8r0  = tid >> 6;
  const int nglob = n0 + ncol;

  // compute geometry: wave (wm,wn) owns 64x32; frags 4m x 2n, 2 k-slices
  const int wm = w >> 1, wn = w & 1;
  const int mb = wm * 64, nb = wn * 32;
  const int fr = lane & 15, fq = lane >> 4;

  f32x4 acc[4][2];
#pragma unroll
  for (int mi = 0; mi < 4; ++mi)
#pragma unroll
    for (int ni = 0; ni < 2; ++ni)
      acc[mi][ni] = (f32x4){0.f, 0.f, 0.f, 0.f};

  u32x4 aPk[4];
  int qa, qb;
  float sv, zv;

  // A: 1024 chunks of 8 elements; thread owns chunks p*256+tid
  auto loadA = [&](int t) {
#pragma unroll
    for (int p = 0; p < 4; ++p) {
      const int ci  = p * 256 + tid;
      const int row = ci >> 3;
      const int c   = ci & 7;
      const float* src = X + (size_t)(m0 + row) * K_DIM + t * BK + c * 8;
      const f32x4 lo = *(const f32x4*)(src);
      const f32x4 hi = *(const f32x4*)(src + 4);
      aPk[p].x = pack_trunc(lo.x, lo.y);
      aPk[p].y = pack_trunc(lo.z, lo.w);
      aPk[p].z = pack_trunc(hi.x, hi.y);
      aPk[p].w = pack_trunc(hi.z, hi.w);
    }
  };
  auto writeA = [&](int buf) {
#pragma unroll
    for (int p = 0; p < 4; ++p) {
      const int ci  = p * 256 + tid;
      const int row = ci >> 3;
      const int c   = ci & 7;
      *(u32x4*)&As[buf][row][c * 8] = aPk[p];
    }
  };
  auto loadB = [&](int t) {
    const int r0 = t * 8 + k8r0;
    qa = QW[(size_t)r0 * N_DIM + nglob];
    qb = QW[(size_t)(r0 + 4) * N_DIM + nglob];
    sv = S[(size_t)(t >> 1) * N_DIM + nglob];  // GROUP_SIZE=128 = 2 K-steps
    zv = Z[(size_t)(t >> 1) * N_DIM + nglob];
  };
  // w = s*q - z == s*(128+q) - (128s+z); f32 bits 0x43000000|nib<<16 == 128+nib exactly
  auto writeB = [&](int buf) {
    const float cc = fmaf(-128.f, sv, -zv);
#pragma unroll
    for (int h = 0; h < 2; ++h) {
      const int q  = h ? qb : qa;
      const int k8 = k8r0 + h * 4;
      float wv[8];
#pragma unroll
      for (int j = 0; j < 8; ++j) {
        const u32 fb = 0x43000000u | (((u32)(q >> (4 * j)) & 0xFu) << 16);
        wv[j] = fmaf(sv, __uint_as_float(fb), cc);
      }
      u32x4 pk;
      pk.x = pack_trunc(wv[0], wv[1]);
      pk.y = pack_trunc(wv[2], wv[3]);
      pk.z = pack_trunc(wv[4], wv[5]);
      pk.w = pack_trunc(wv[6], wv[7]);
      *(u32x4*)&Bs[buf][ncol][k8 * 8] = pk;
    }
  };

  // prologue
  loadA(0); loadB(0);
  writeA(0); writeB(0);
  __syncthreads();

  for (int t = 0; t < NT; ++t) {
    const int cur = t & 1;
    const bool pf = (t + 1 < NT);
    if (pf) { loadA(t + 1); loadB(t + 1); }   // issue global loads early (T14)

#pragma unroll
    for (int ks = 0; ks < 2; ++ks) {
      bf16x8 af[4], bv[2];
#pragma unroll
      for (int mi = 0; mi < 4; ++mi)
        af[mi] = *(const bf16x8*)&As[cur][mb + mi * 16 + fr][ks * 32 + fq * 8];
#pragma unroll
      for (int ni = 0; ni < 2; ++ni)
        bv[ni] = *(const bf16x8*)&Bs[cur][nb + ni * 16 + fr][ks * 32 + fq * 8];
#pragma unroll
      for (int mi = 0; mi < 4; ++mi)
#pragma unroll
        for (int ni = 0; ni < 2; ++ni)
          acc[mi][ni] = __builtin_amdgcn_mfma_f32_16x16x32_bf16(
              af[mi], bv[ni], acc[mi][ni], 0, 0, 0);
    }

    if (pf) { writeA(cur ^ 1); writeB(cur ^ 1); }  // write next tile after compute
    __syncthreads();
  }

  // epilogue: C/D layout col=lane&15, row=(lane>>4)*4+r (m89-verified)
#pragma unroll
  for (int mi = 0; mi < 4; ++mi)
#pragma unroll
    for (int ni = 0; ni < 2; ++ni)
#pragma unroll
      for (int r = 0; r < 4; ++r) {
        const int row = m0 + mb + mi * 16 + fq * 4 + r;
        const int col = n0 + nb + ni * 16 + fr;
        O[(size_t)row * N_DIM + col] = acc[mi][ni][r];
      }
}

extern "C" void kernel_launch(void* const* d_in, const int* in_sizes, int n_in,
                              void* d_out, int out_size, void* d_ws, size_t ws_size,
                              hipStream_t stream) {
  const float* X  = (const float*)d_in[0];
  const int*   QW = (const int*)d_in[1];
  const float* S  = (const float*)d_in[2];
  const float* Zp = (const float*)d_in[3];
  float* O = (float*)d_out;
  hipLaunchKernelGGL(kivi_gemm, dim3(NBLK), dim3(256), 0, stream, X, QW, S, Zp, O);
}

// Round 5
// 65.312 us; speedup vs baseline: 1.1893x; 1.1893x over previous
//
#include <hip/hip_runtime.h>
#include <hip/hip_fp16.h>

typedef unsigned int u32;
typedef unsigned short u16;
typedef __attribute__((ext_vector_type(8))) _Float16 f16x8;
typedef __attribute__((ext_vector_type(4))) float f32x4;
typedef __attribute__((ext_vector_type(4))) u32 u32x4;

#define K_DIM 4096
#define N_DIM 14336
#define BM 128
#define BN 64
#define BK 64
#define NT 64             // K-steps
#define NBLK 448          // (256/128) * (14336/64)
#define LDA 72            // padded row stride in f16 (144 B)
#define LDB 72

union H2U { u32 u; __half2 h; };

__device__ __forceinline__ u32 pkrtz(float a, float b) {  // exact: x was f16
  return __builtin_bit_cast(u32, __builtin_amdgcn_cvt_pkrtz(a, b));
}

// dequant 2 nibbles (bits 0-3 = k even, bits 4-7 = k odd) via packed f16 fma
__device__ __forceinline__ u32 dq2(u32 t, __half2 s2, __half2 c2) {
  H2U x; x.u = 0x58005800u | ((t & 0xFu) << 3) | ((t & 0xF0u) << 15);  // {128+qlo,128+qhi}
  H2U r; r.h = __hfma2(s2, x.h, c2);   // s*(128+q) - (128s+z)  ==  s*q - z
  return r.u;
}

__global__ __launch_bounds__(512, 4) void kivi_gemm(
    const float* __restrict__ X,    // x upconverted to f32 [256][4096]
    const int* __restrict__ QW,     // [512][14336] nibble j of row r -> k = r*8+j
    const float* __restrict__ S,    // [32][14336]
    const float* __restrict__ Z,    // [32][14336]
    float* __restrict__ O)          // out f32 [256][14336]
{
  __shared__ __align__(16) u16 As[2][BM][LDA];  // 36,864 B (one buffer per K-set)
  __shared__ __align__(16) u16 Bs[2][BN][LDB];  // 18,432 B

  const int tid  = threadIdx.x;
  const int lane = tid & 63;
  const int w    = tid >> 6;
  const int ws   = w >> 2;          // K-slice set: 0 -> even K-steps, 1 -> odd
  const int wl   = w & 3;           // wave within set
  const int stid = tid & 255;       // thread id within set

  // XCD-aware bijective swizzle: 448 = 8*56
  const int b  = blockIdx.x;
  const int L  = (b & 7) * 56 + (b >> 3);
  const int m0 = (L & 1) * BM;
  const int n0 = (L >> 1) * BN;

  // B staging ownership (within set)
  const int ncol  = stid & 63;
  const int k8r0  = stid >> 6;
  const int nglob = n0 + ncol;

  // compute geometry: wave owns 64x32; frags 4m x 2n, 2 k-slices
  const int wm = wl >> 1, wn = wl & 1;
  const int mb = wm * 64, nb = wn * 32;
  const int fr = lane & 15, fq = lane >> 4;

  f32x4 acc[4][2];
#pragma unroll
  for (int mi = 0; mi < 4; ++mi)
#pragma unroll
    for (int ni = 0; ni < 2; ++ni)
      acc[mi][ni] = (f32x4){0.f, 0.f, 0.f, 0.f};

  u32x4 aPk[4];
  int qa, qb;
  float sv, zv;

  auto loadA = [&](int t) {
#pragma unroll
    for (int p = 0; p < 4; ++p) {
      const int ci  = p * 256 + stid;      // 1024 chunks of 8 f16
      const int row = ci >> 3;
      const int c   = ci & 7;
      const float* src = X + (size_t)(m0 + row) * K_DIM + t * BK + c * 8;
      const f32x4 lo = *(const f32x4*)(src);
      const f32x4 hi = *(const f32x4*)(src + 4);
      aPk[p].x = pkrtz(lo.x, lo.y);
      aPk[p].y = pkrtz(lo.z, lo.w);
      aPk[p].z = pkrtz(hi.x, hi.y);
      aPk[p].w = pkrtz(hi.z, hi.w);
    }
  };
  auto writeA = [&]() {
#pragma unroll
    for (int p = 0; p < 4; ++p) {
      const int ci  = p * 256 + stid;
      const int row = ci >> 3;
      const int c   = ci & 7;
      *(u32x4*)&As[ws][row][c * 8] = aPk[p];
    }
  };
  auto loadB = [&](int t) {
    const int r0 = t * 8 + k8r0;
    qa = QW[(size_t)r0 * N_DIM + nglob];
    qb = QW[(size_t)(r0 + 4) * N_DIM + nglob];
    sv = S[(size_t)(t >> 1) * N_DIM + nglob];   // GROUP_SIZE=128 = 2 K-steps
    zv = Z[(size_t)(t >> 1) * N_DIM + nglob];
  };
  auto writeB = [&]() {
    const __half sh = __float2half(sv);                       // matches ref astype(f16)
    const __half ch = __float2half(fmaf(-128.f, sv, -zv));    // -(128s+z)
    const __half2 s2 = __halves2half2(sh, sh);
    const __half2 c2 = __halves2half2(ch, ch);
#pragma unroll
    for (int h = 0; h < 2; ++h) {
      const u32 q  = (u32)(h ? qb : qa);
      const int k8 = k8r0 + h * 4;
      u32x4 pk;
      pk.x = dq2(q,       s2, c2);
      pk.y = dq2(q >> 8,  s2, c2);
      pk.z = dq2(q >> 16, s2, c2);
      pk.w = dq2(q >> 24, s2, c2);
      *(u32x4*)&Bs[ws][ncol][k8 * 8] = pk;
    }
  };

  // prologue: set ws stages K-step t=ws into its buffer
  loadA(ws); loadB(ws);
  writeA(); writeB();
  __syncthreads();

  for (int i = 0; i < NT / 2; ++i) {
    const bool pf = (i + 1 < NT / 2);
    if (pf) { loadA(2 * i + 2 + ws); loadB(2 * i + 2 + ws); }  // globals early (T14)

#pragma unroll
    for (int ks = 0; ks < 2; ++ks) {
      f16x8 af[4], bv[2];
#pragma unroll
      for (int mi = 0; mi < 4; ++mi)
        af[mi] = *(const f16x8*)&As[ws][mb + mi * 16 + fr][ks * 32 + fq * 8];
#pragma unroll
      for (int ni = 0; ni < 2; ++ni)
        bv[ni] = *(const f16x8*)&Bs[ws][nb + ni * 16 + fr][ks * 32 + fq * 8];
#pragma unroll
      for (int mi = 0; mi < 4; ++mi)
#pragma unroll
        for (int ni = 0; ni < 2; ++ni)
          acc[mi][ni] = __builtin_amdgcn_mfma_f32_16x16x32_f16(
              af[mi], bv[ni], acc[mi][ni], 0, 0, 0);
    }

    __syncthreads();                      // all sets done reading their buffers
    if (pf) { writeA(); writeB(); }       // overwrite own buffer with t+2
    __syncthreads();                      // writes visible
  }

  // cross-set reduction: set 1 -> LDS, set 0 adds and stores
  float (*Lr)[68] = reinterpret_cast<float(*)[68]>(&As[0][0][0]);  // 128*68*4=34816 B
  if (ws == 1) {
#pragma unroll
    for (int mi = 0; mi < 4; ++mi)
#pragma unroll
      for (int ni = 0; ni < 2; ++ni)
#pragma unroll
        for (int r = 0; r < 4; ++r)
          Lr[mb + mi * 16 + fq * 4 + r][nb + ni * 16 + fr] = acc[mi][ni][r];
  }
  __syncthreads();
  if (ws == 0) {
#pragma unroll
    for (int mi = 0; mi < 4; ++mi)
#pragma unroll
      for (int ni = 0; ni < 2; ++ni)
#pragma unroll
        for (int r = 0; r < 4; ++r) {
          const int row = mb + mi * 16 + fq * 4 + r;
          const int col = nb + ni * 16 + fr;
          O[(size_t)(m0 + row) * N_DIM + n0 + col] = acc[mi][ni][r] + Lr[row][col];
        }
  }
}

extern "C" void kernel_launch(void* const* d_in, const int* in_sizes, int n_in,
                              void* d_out, int out_size, void* d_ws, size_t ws_size,
                              hipStream_t stream) {
  const float* X  = (const float*)d_in[0];
  const int*   QW = (const int*)d_in[1];
  const float* S  = (const float*)d_in[2];
  const float* Zp = (const float*)d_in[3];
  float* O = (float*)d_out;
  hipLaunchKernelGGL(kivi_gemm, dim3(NBLK), dim3(512), 0, stream, X, QW, S, Zp, O);
}